// Round 3
// baseline (1452.610 us; speedup 1.0000x reference)
//
#include <hip/hip_runtime.h>
#include <math.h>

typedef unsigned short u16;
typedef __bf16 bf16x8 __attribute__((ext_vector_type(8)));
typedef float f32x4  __attribute__((ext_vector_type(4)));
typedef float f32x16 __attribute__((ext_vector_type(16)));
typedef u16   u16x4  __attribute__((ext_vector_type(4)));

#define GPTR(p) ((__attribute__((address_space(1))) void*)(p))
#define LPTR(p) ((__attribute__((address_space(3))) void*)(p))

__device__ __forceinline__ float bf2f(u16 h) { return __uint_as_float(((unsigned)h) << 16); }
__device__ __forceinline__ u16 f2bf(float f) {
    unsigned u = __float_as_uint(f);
    return (u16)((u + 0x7fffu + ((u >> 16) & 1u)) >> 16);
}
// tanh-form gelu, ~8 VALU ops
__device__ __forceinline__ float gelu_f(float x) {
    float u = 0.7978845608f * x * (1.0f + 0.044715f * x * x);
    float e = __expf(2.0f * u);
    float t = 1.0f - 2.0f / (e + 1.0f);
    return 0.5f * x * (1.0f + t);
}

// ---------------------------------------------------------------------------
// GEMM: C = epilogue(A(MxK) @ B(NxK)^T), bf16 in, fp32 acc.
// 128x128 block tile, 4 waves of 64x64, BK=32, mfma_f32_32x32x16_bf16.
// LDS tile stored in MFMA-operand granule order:
//   granule g(16B) = rowblk*128 + kh*64 + h*32 + row32
//   (row = rowblk*32+row32, k-chunk kc = kh*2+h, elements kc*8..kc*8+7)
// -> fragment ds_read_b128 is base+lane*16 (conflict-free)
// -> staging global_load_lds dest is base+t*16 (wave-uniform+lane*16, legal,
//    conflict-free)
// Epilogue: per-wave 4KB LDS slice, acc frag round-trip f32, wide stores.
// MODE: 0=none, 1=scale, 2=+bias, 3=+bias,gelu, 4=+bias,gelu,+addend, 5=+bias fp32-out
// ---------------------------------------------------------------------------
template<int MODE>
__global__ __launch_bounds__(256, 4)
void gemm_bt(const u16* __restrict__ A, int lda, long sA,
             const u16* __restrict__ B, int ldb, long sB,
             void* __restrict__ Cout, int ldc, long sC,
             const float* __restrict__ bias,
             const u16* __restrict__ addend,
             int K, float scale)
{
    __shared__ u16 lds[8192];           // 16 KB: lA=[0,4096), lB=[4096,8192)
    u16* lA = lds;
    u16* lB = lds + 4096;
    const int t    = threadIdx.x;
    const int lane = t & 63;
    const int wid  = t >> 6;
    const int wm   = (wid & 1) * 64;
    const int wn   = (wid >> 1) * 64;
    const int m32  = lane & 31;
    const int h    = lane >> 5;
    const int bz   = blockIdx.z;

    const long rowA0 = (long)blockIdx.y * 128;
    const long colB0 = (long)blockIdx.x * 128;
    const u16* Ab = A + (long)bz * sA + rowA0 * lda;
    const u16* Bb = B + (long)bz * sB + colB0 * ldb;

    // staging: thread t loads granule t (inst0) and granule 256+t (inst1)
    const int row0 = ((t >> 7) << 5) | (t & 31);   // 0..63
    const int kcEl = ((t >> 5) & 3) * 8;           // k element offset 0/8/16/24
    const u16* gA0 = Ab + (long)row0 * lda + kcEl;
    const u16* gA1 = Ab + (long)(64 + row0) * lda + kcEl;
    const u16* gB0 = Bb + (long)row0 * ldb + kcEl;
    const u16* gB1 = Bb + (long)(64 + row0) * ldb + kcEl;
    u16* dA0 = lA + t * 8;
    u16* dA1 = lA + 2048 + t * 8;
    u16* dB0 = lB + t * 8;
    u16* dB1 = lB + 2048 + t * 8;

    f32x16 acc[2][2];
    #pragma unroll
    for (int i = 0; i < 2; i++)
        #pragma unroll
        for (int j = 0; j < 2; j++)
            #pragma unroll
            for (int r = 0; r < 16; r++) acc[i][j][r] = 0.f;

    // fragment bases: elem offset = wm*32 + lane*8 (+ mi*1024 + kh*512)
    const u16* fA = lA + wm * 32 + lane * 8;
    const u16* fB = lB + wn * 32 + lane * 8;

    for (int k0 = 0; k0 < K; k0 += 32) {
        __builtin_amdgcn_global_load_lds(GPTR(gA0 + k0), LPTR(dA0), 16, 0, 0);
        __builtin_amdgcn_global_load_lds(GPTR(gA1 + k0), LPTR(dA1), 16, 0, 0);
        __builtin_amdgcn_global_load_lds(GPTR(gB0 + k0), LPTR(dB0), 16, 0, 0);
        __builtin_amdgcn_global_load_lds(GPTR(gB1 + k0), LPTR(dB1), 16, 0, 0);
        __syncthreads();
        bf16x8 a[2][2], b[2][2];
        #pragma unroll
        for (int mi = 0; mi < 2; mi++)
            #pragma unroll
            for (int kh = 0; kh < 2; kh++)
                a[mi][kh] = *(const bf16x8*)(fA + mi * 1024 + kh * 512);
        #pragma unroll
        for (int ni = 0; ni < 2; ni++)
            #pragma unroll
            for (int kh = 0; kh < 2; kh++)
                b[ni][kh] = *(const bf16x8*)(fB + ni * 1024 + kh * 512);
        #pragma unroll
        for (int mi = 0; mi < 2; mi++)
            #pragma unroll
            for (int ni = 0; ni < 2; ni++)
                #pragma unroll
                for (int kh = 0; kh < 2; kh++)
                    acc[mi][ni] = __builtin_amdgcn_mfma_f32_32x32x16_bf16(a[mi][kh], b[ni][kh], acc[mi][ni], 0, 0, 0);
        __syncthreads();
    }
    // final barrier of loop guarantees all tile reads done -> safe to reuse lds

    float* Cf = (float*)Cout + (long)bz * sC;
    u16*   Cu = (u16*)Cout + (long)bz * sC;
    float* sw_ = (float*)lds + wid * 1024;      // per-wave 4KB slice
    const long rb = rowA0 + wm;
    const long cb = colB0 + wn;
    const int prow = lane >> 3;                 // 0..7
    const int c4   = (lane & 7) * 4;            // col offset 0..28
    // C/D layout (m74/m101): col = lane&31, row = (reg&3) + 8*(reg>>2) + 4*(lane>>5)
    #pragma unroll
    for (int mi = 0; mi < 2; mi++) {
        #pragma unroll
        for (int ni = 0; ni < 2; ni++) {
            #pragma unroll
            for (int r = 0; r < 16; r++)
                sw_[((r & 3) + 8 * (r >> 2) + 4 * h) * 32 + m32] = acc[mi][ni][r];
            #pragma unroll
            for (int p = 0; p < 4; p++) {
                const int  row  = p * 8 + prow;
                const long grow = rb + mi * 32 + row;
                const long gcol = cb + ni * 32 + c4;
                f32x4 v = *(const f32x4*)&sw_[row * 32 + c4];
                float4 bvv = {0.f, 0.f, 0.f, 0.f};
                if constexpr (MODE >= 2) bvv = *(const float4*)&bias[gcol];
                if constexpr (MODE == 1) {
                    #pragma unroll
                    for (int e = 0; e < 4; e++) v[e] *= scale;
                }
                v[0] += bvv.x; v[1] += bvv.y; v[2] += bvv.z; v[3] += bvv.w;
                if constexpr (MODE == 3 || MODE == 4) {
                    #pragma unroll
                    for (int e = 0; e < 4; e++) v[e] = gelu_f(v[e]);
                }
                if constexpr (MODE == 4) {
                    u16x4 ad = *(const u16x4*)&addend[grow * (long)ldc + gcol];
                    #pragma unroll
                    for (int e = 0; e < 4; e++) v[e] += bf2f(ad[e]);
                }
                if constexpr (MODE == 5) {
                    *(f32x4*)&Cf[grow * (long)ldc + gcol] = v;
                } else {
                    u16x4 o = { f2bf(v[0]), f2bf(v[1]), f2bf(v[2]), f2bf(v[3]) };
                    *(u16x4*)&Cu[grow * (long)ldc + gcol] = o;
                }
            }
        }
    }
}

// one launch converting all five fp32->bf16 segments
__global__ __launch_bounds__(256)
void cvt_all(const float* __restrict__ s0, u16* __restrict__ d0, long n0,
             const float* __restrict__ s1, u16* __restrict__ d1, long n1,
             const float* __restrict__ s2, u16* __restrict__ d2, long n2,
             const float* __restrict__ s3, u16* __restrict__ d3, long n3,
             const float* __restrict__ s4, u16* __restrict__ d4, long n4)
{
    long i = ((long)blockIdx.x * 256 + threadIdx.x) * 4;
    const float* s; u16* d;
    if      (i < n0)                    { s = s0;  d = d0; }
    else if ((i -= n0) < n1)            { s = s1;  d = d1; }
    else if ((i -= n1) < n2)            { s = s2;  d = d2; }
    else if ((i -= n2) < n3)            { s = s3;  d = d3; }
    else if ((i -= n3) < n4)            { s = s4;  d = d4; }
    else return;
    float4 v = *(const float4*)(s + i);
    u16x4 o = { f2bf(v.x), f2bf(v.y), f2bf(v.z), f2bf(v.w) };
    *(u16x4*)(d + i) = o;
}

__global__ __launch_bounds__(256)
void ln_kernel(const u16* __restrict__ in, u16* __restrict__ out,
               const float* __restrict__ g, const float* __restrict__ b)
{
    const int row = blockIdx.x;
    const int t = threadIdx.x;
    const u16* r = in + (long)row * 1024;
    float x[4];
    float s = 0.f, s2 = 0.f;
    #pragma unroll
    for (int j = 0; j < 4; j++) { x[j] = bf2f(r[t + 256 * j]); s += x[j]; s2 += x[j] * x[j]; }
    __shared__ float sm[8];
    const int lane = t & 63, wid = t >> 6;
    #pragma unroll
    for (int o = 32; o > 0; o >>= 1) { s += __shfl_down(s, o, 64); s2 += __shfl_down(s2, o, 64); }
    if (lane == 0) { sm[wid] = s; sm[4 + wid] = s2; }
    __syncthreads();
    s  = sm[0] + sm[1] + sm[2] + sm[3];
    s2 = sm[4] + sm[5] + sm[6] + sm[7];
    const float mean = s * (1.f / 1024.f);
    const float var  = s2 * (1.f / 1024.f) - mean * mean;
    const float rstd = rsqrtf(var + 1e-5f);
    u16* o = out + (long)row * 1024;
    #pragma unroll
    for (int j = 0; j < 4; j++) {
        int c = t + 256 * j;
        o[c] = f2bf((x[j] - mean) * rstd * g[c] + b[c]);
    }
}

__global__ __launch_bounds__(256)
void softmax_kernel(u16* __restrict__ io)
{
    const int row = blockIdx.x;
    const int t = threadIdx.x;
    u16* r = io + (long)row * 1024;
    float x[4];
    float m = -1e30f;
    #pragma unroll
    for (int j = 0; j < 4; j++) { x[j] = bf2f(r[t + 256 * j]); m = fmaxf(m, x[j]); }
    __shared__ float sm[8];
    const int lane = t & 63, wid = t >> 6;
    #pragma unroll
    for (int o = 32; o > 0; o >>= 1) m = fmaxf(m, __shfl_down(m, o, 64));
    if (lane == 0) sm[wid] = m;
    __syncthreads();
    m = fmaxf(fmaxf(sm[0], sm[1]), fmaxf(sm[2], sm[3]));
    float e[4];
    float s = 0.f;
    #pragma unroll
    for (int j = 0; j < 4; j++) { e[j] = __expf(x[j] - m); s += e[j]; }
    #pragma unroll
    for (int o = 32; o > 0; o >>= 1) s += __shfl_down(s, o, 64);
    if (lane == 0) sm[4 + wid] = s;
    __syncthreads();
    s = sm[4] + sm[5] + sm[6] + sm[7];
    const float inv = 1.f / s;
    #pragma unroll
    for (int j = 0; j < 4; j++) r[t + 256 * j] = f2bf(e[j] * inv);
}

// vT[b][c][t] = qkv[b*S + t][2C + c]
__global__ void transpose_v(const u16* __restrict__ qkv, u16* __restrict__ vT)
{
    __shared__ u16 tile[32][33];
    const int b  = blockIdx.z;
    const int t0 = blockIdx.x * 32;   // S index
    const int c0 = blockIdx.y * 32;   // C index
    const int tx = threadIdx.x, ty = threadIdx.y;
    #pragma unroll
    for (int i = ty; i < 32; i += 8)
        tile[i][tx] = qkv[((long)(b * 2048 + t0 + i)) * 3072 + 2048 + c0 + tx];
    __syncthreads();
    #pragma unroll
    for (int i = ty; i < 32; i += 8)
        vT[((long)(b * 1024 + c0 + i)) * 2048 + t0 + tx] = tile[tx][i];
}

__global__ __launch_bounds__(256)
void add_pe(float* __restrict__ out)
{
    long i = (long)blockIdx.x * 256 + threadIdx.x;
    const int f = (int)(i & 1023);
    const int s = (int)((i >> 10) & 2047);
    const float div = __expf(-(float)f * 0.013491709529261986f);
    const float arg = (float)s * div;
    const float pe = (s & 1) ? cosf(arg) : sinf(arg);
    out[i] += pe;
}

extern "C" void kernel_launch(void* const* d_in, const int* in_sizes, int n_in,
                              void* d_out, int out_size, void* d_ws, size_t ws_size,
                              hipStream_t stream)
{
    const float* x        = (const float*)d_in[0];
    const float* fc_in_w  = (const float*)d_in[1];
    const float* fc_in_b  = (const float*)d_in[2];
    const float* ln_g     = (const float*)d_in[3];
    const float* ln_b     = (const float*)d_in[4];
    const float* qkv_w    = (const float*)d_in[5];
    const float* qkv_b    = (const float*)d_in[6];
    const float* proj_w   = (const float*)d_in[7];
    const float* proj_b   = (const float*)d_in[8];
    const float* fc_out_w = (const float*)d_in[9];
    const float* fc_out_b = (const float*)d_in[10];

    char* w = (char*)d_ws;
    size_t off = 0;
    auto carve = [&](size_t bytes) -> void* {
        void* p = w + off;
        off += (bytes + 255) & ~(size_t)255;
        return p;
    };
    u16* xb   = (u16*)carve(16777216);  // x bf16; reused as hY
    u16* hY   = xb;
    u16* wfci = (u16*)carve(2097152);
    u16* wqkv = (u16*)carve(25165824);
    u16* wprj = (u16*)carve(8388608);
    u16* wfco = (u16*)carve(2097152);
    u16* t0   = (u16*)carve(50331648);  // qkv acts (8192x3072); att aliases
    u16* att  = t0;
    u16* hX   = (u16*)carve(16777216);
    u16* pred = (u16*)carve(16777216);
    u16* vT   = (u16*)carve(16777216);  // (B, C, S)
    u16* sc   = (u16*)carve(33554432);  // scores (B, S, S)

    // fp32 -> bf16, one launch
    cvt_all<<<dim3(26624), dim3(256), 0, stream>>>(
        x, xb, 8388608L, fc_in_w, wfci, 1048576L, qkv_w, wqkv, 12582912L,
        proj_w, wprj, 4194304L, fc_out_w, wfco, 1048576L);

    // fc_in: t0 = x @ fc_in_w^T + b   (8192x1024, K=1024)
    gemm_bt<2><<<dim3(8, 64, 1), 256, 0, stream>>>(xb, 1024, 0, wfci, 1024, 0,
                                                   t0, 1024, 0, fc_in_b, nullptr, 1024, 1.0f);
    ln_kernel<<<8192, 256, 0, stream>>>(t0, hX, ln_g, ln_b);

    const u16* hin[4] = { hX, pred, hX, hY };
    u16* hout[4]      = { pred, hX, hY, hX };

    for (int i = 0; i < 4; i++) {
        // qkv = gelu(h @ qkv_w[i]^T + qkv_b[i])  (8192x3072, K=1024)
        gemm_bt<3><<<dim3(24, 64, 1), 256, 0, stream>>>(hin[i], 1024, 0,
            wqkv + (long)i * 3145728, 1024, 0, t0, 3072, 0,
            qkv_b + (long)i * 3072, nullptr, 1024, 1.0f);
        transpose_v<<<dim3(64, 32, 4), dim3(32, 8), 0, stream>>>(t0, vT);
        // scores = q @ k^T * (1/C)   (per batch 2048x2048, K=1024)
        gemm_bt<1><<<dim3(16, 16, 4), 256, 0, stream>>>(t0, 3072, 6291456,
            t0 + 1024, 3072, 6291456, sc, 2048, 4194304,
            nullptr, nullptr, 1024, 1.0f / 1024.0f);
        // att = scores @ v   (per batch 2048x1024, K=2048)
        gemm_bt<0><<<dim3(8, 16, 4), 256, 0, stream>>>(sc, 2048, 4194304,
            vT, 2048, 2097152, att, 1024, 2097152,
            nullptr, nullptr, 2048, 1.0f);
        softmax_kernel<<<8192, 256, 0, stream>>>(att);
        // h = gelu(att @ proj_w[i]^T + proj_b[i]) [+ pred for i>0]
        if (i == 0)
            gemm_bt<3><<<dim3(8, 64, 1), 256, 0, stream>>>(att, 1024, 0,
                wprj, 1024, 0, hout[0], 1024, 0, proj_b, nullptr, 1024, 1.0f);
        else
            gemm_bt<4><<<dim3(8, 64, 1), 256, 0, stream>>>(att, 1024, 0,
                wprj + (long)i * 1048576, 1024, 0, hout[i], 1024, 0,
                proj_b + (long)i * 1024, pred, 1024, 1.0f);
    }

    gemm_bt<5><<<dim3(8, 64, 1), 256, 0, stream>>>(hX, 1024, 0, wfco, 1024, 0,
                                                   d_out, 1024, 0, fc_out_b, nullptr, 1024, 1.0f);
    add_pe<<<32768, 256, 0, stream>>>((float*)d_out);
}

// Round 4
// 1069.567 us; speedup vs baseline: 1.3581x; 1.3581x over previous
//
#include <hip/hip_runtime.h>
#include <math.h>

typedef unsigned short u16;
typedef __bf16 bf16x8 __attribute__((ext_vector_type(8)));
typedef float f32x4  __attribute__((ext_vector_type(4)));
typedef float f32x16 __attribute__((ext_vector_type(16)));
typedef u16   u16x4  __attribute__((ext_vector_type(4)));

#define GPTR(p) ((__attribute__((address_space(1))) void*)(p))
#define LPTR(p) ((__attribute__((address_space(3))) void*)(p))

__device__ __forceinline__ float bf2f(u16 h) { return __uint_as_float(((unsigned)h) << 16); }
__device__ __forceinline__ u16 f2bf(float f) {
    unsigned u = __float_as_uint(f);
    return (u16)((u + 0x7fffu + ((u >> 16) & 1u)) >> 16);
}
// tanh-form gelu, ~8 VALU ops
__device__ __forceinline__ float gelu_f(float x) {
    float u = 0.7978845608f * x * (1.0f + 0.044715f * x * x);
    float e = __expf(2.0f * u);
    float t = 1.0f - 2.0f / (e + 1.0f);
    return 0.5f * x * (1.0f + t);
}

// ---------------------------------------------------------------------------
// GEMM: C = epilogue(A(MxK) @ B(NxK)^T), bf16 in, fp32 acc.
// 128x128 block tile, 4 waves of 64x64, BK=64, mfma_f32_32x32x16_bf16.
// LDS per operand tile: 128 rows x 64 k = 1024 granules of 16B.
//   slot(row, kc) = row*8 + (kc ^ (row & 7)),  kc = k-chunk 0..7 (8 elems each)
// Staging (global_load_lds, dest = base + t*16): inst j, thread t ->
//   slot j*256+t -> row = j*32 + (t>>3), kc = (t&7) ^ ((t>>3)&7)
//   => 8 consecutive lanes read one row's 128B contiguous (full coalescing).
// Fragment read (kh=k-step, h=lane>>5): chunk kc = kh*2+h at
//   addr = row*64 + 8*(kc ^ (m32&7)) elems; bank-group = kc ^ (m32&7)
//   => 8 distinct per 8-lane phase (conflict-free).
// Epilogue: per-wave 4KB LDS slice round-trip, wide stores.
// MODE: 0=none, 1=scale, 2=+bias, 3=+bias,gelu, 4=+bias,gelu,+addend, 5=+bias fp32-out
// ---------------------------------------------------------------------------
template<int MODE>
__global__ __launch_bounds__(256, 4)
void gemm_bt(const u16* __restrict__ A, int lda, long sA,
             const u16* __restrict__ B, int ldb, long sB,
             void* __restrict__ Cout, int ldc, long sC,
             const float* __restrict__ bias,
             const u16* __restrict__ addend,
             int K, float scale)
{
    __shared__ u16 lds[16384];          // 32 KB: lA=[0,8192), lB=[8192,16384)
    u16* lA = lds;
    u16* lB = lds + 8192;
    const int t    = threadIdx.x;
    const int lane = t & 63;
    const int wid  = t >> 6;
    const int wm   = (wid & 1) * 64;
    const int wn   = (wid >> 1) * 64;
    const int m32  = lane & 31;
    const int h    = lane >> 5;
    const int bz   = blockIdx.z;

    const long rowA0 = (long)blockIdx.y * 128;
    const long colB0 = (long)blockIdx.x * 128;
    const u16* Ab = A + (long)bz * sA + rowA0 * lda;
    const u16* Bb = B + (long)bz * sB + colB0 * ldb;

    // staging: inst j (j=0..3 per operand), thread t -> row j*32+(t>>3),
    // global chunk (t&7)^((t>>3)&7), LDS slot j*256+t.
    const int rt  = t >> 3;                       // 0..31
    const int kcg = ((t & 7) ^ (rt & 7)) * 8;     // element offset in row
    const u16* gA[4]; const u16* gB[4];
    #pragma unroll
    for (int j = 0; j < 4; j++) {
        gA[j] = Ab + (long)(j * 32 + rt) * lda + kcg;
        gB[j] = Bb + (long)(j * 32 + rt) * ldb + kcg;
    }
    u16* dA = lA + t * 8;
    u16* dB = lB + t * 8;

    f32x16 acc[2][2];
    #pragma unroll
    for (int i = 0; i < 2; i++)
        #pragma unroll
        for (int j = 0; j < 2; j++)
            #pragma unroll
            for (int r = 0; r < 16; r++) acc[i][j][r] = 0.f;

    // fragment base addresses per k-step kh: row*64 + 8*((kh*2+h)^(m32&7))
    const int sg = m32 & 7;
    const u16* fA[4]; const u16* fB[4];
    #pragma unroll
    for (int kh = 0; kh < 4; kh++) {
        fA[kh] = lA + (wm + m32) * 64 + 8 * ((kh * 2 + h) ^ sg);
        fB[kh] = lB + (wn + m32) * 64 + 8 * ((kh * 2 + h) ^ sg);
    }

    for (int k0 = 0; k0 < K; k0 += 64) {
        #pragma unroll
        for (int j = 0; j < 4; j++) {
            __builtin_amdgcn_global_load_lds(GPTR(gA[j] + k0), LPTR(dA + j * 2048), 16, 0, 0);
            __builtin_amdgcn_global_load_lds(GPTR(gB[j] + k0), LPTR(dB + j * 2048), 16, 0, 0);
        }
        __syncthreads();
        #pragma unroll
        for (int kh = 0; kh < 4; kh++) {
            bf16x8 a0 = *(const bf16x8*)(fA[kh]);
            bf16x8 a1 = *(const bf16x8*)(fA[kh] + 2048);
            bf16x8 b0 = *(const bf16x8*)(fB[kh]);
            bf16x8 b1 = *(const bf16x8*)(fB[kh] + 2048);
            acc[0][0] = __builtin_amdgcn_mfma_f32_32x32x16_bf16(a0, b0, acc[0][0], 0, 0, 0);
            acc[0][1] = __builtin_amdgcn_mfma_f32_32x32x16_bf16(a0, b1, acc[0][1], 0, 0, 0);
            acc[1][0] = __builtin_amdgcn_mfma_f32_32x32x16_bf16(a1, b0, acc[1][0], 0, 0, 0);
            acc[1][1] = __builtin_amdgcn_mfma_f32_32x32x16_bf16(a1, b1, acc[1][1], 0, 0, 0);
        }
        __syncthreads();
    }
    // final barrier guarantees all tile reads done -> safe to reuse lds

    float* Cf = (float*)Cout + (long)bz * sC;
    u16*   Cu = (u16*)Cout + (long)bz * sC;
    float* sw_ = (float*)lds + wid * 1024;      // per-wave 4KB slice
    const long rb = rowA0 + wm;
    const long cb = colB0 + wn;
    const int prow = lane >> 3;                 // 0..7
    const int c4   = (lane & 7) * 4;            // col offset 0..28
    // C/D layout (m74/m101): col = lane&31, row = (reg&3) + 8*(reg>>2) + 4*(lane>>5)
    #pragma unroll
    for (int mi = 0; mi < 2; mi++) {
        #pragma unroll
        for (int ni = 0; ni < 2; ni++) {
            #pragma unroll
            for (int r = 0; r < 16; r++)
                sw_[((r & 3) + 8 * (r >> 2) + 4 * h) * 32 + m32] = acc[mi][ni][r];
            #pragma unroll
            for (int p = 0; p < 4; p++) {
                const int  row  = p * 8 + prow;
                const long grow = rb + mi * 32 + row;
                const long gcol = cb + ni * 32 + c4;
                f32x4 v = *(const f32x4*)&sw_[row * 32 + c4];
                float4 bvv = {0.f, 0.f, 0.f, 0.f};
                if constexpr (MODE >= 2) bvv = *(const float4*)&bias[gcol];
                if constexpr (MODE == 1) {
                    #pragma unroll
                    for (int e = 0; e < 4; e++) v[e] *= scale;
                }
                v[0] += bvv.x; v[1] += bvv.y; v[2] += bvv.z; v[3] += bvv.w;
                if constexpr (MODE == 3 || MODE == 4) {
                    #pragma unroll
                    for (int e = 0; e < 4; e++) v[e] = gelu_f(v[e]);
                }
                if constexpr (MODE == 4) {
                    u16x4 ad = *(const u16x4*)&addend[grow * (long)ldc + gcol];
                    #pragma unroll
                    for (int e = 0; e < 4; e++) v[e] += bf2f(ad[e]);
                }
                if constexpr (MODE == 5) {
                    *(f32x4*)&Cf[grow * (long)ldc + gcol] = v;
                } else {
                    u16x4 o = { f2bf(v[0]), f2bf(v[1]), f2bf(v[2]), f2bf(v[3]) };
                    *(u16x4*)&Cu[grow * (long)ldc + gcol] = o;
                }
            }
        }
    }
}

// one launch converting all five fp32->bf16 segments
__global__ __launch_bounds__(256)
void cvt_all(const float* __restrict__ s0, u16* __restrict__ d0, long n0,
             const float* __restrict__ s1, u16* __restrict__ d1, long n1,
             const float* __restrict__ s2, u16* __restrict__ d2, long n2,
             const float* __restrict__ s3, u16* __restrict__ d3, long n3,
             const float* __restrict__ s4, u16* __restrict__ d4, long n4)
{
    long i = ((long)blockIdx.x * 256 + threadIdx.x) * 4;
    const float* s; u16* d;
    if      (i < n0)                    { s = s0;  d = d0; }
    else if ((i -= n0) < n1)            { s = s1;  d = d1; }
    else if ((i -= n1) < n2)            { s = s2;  d = d2; }
    else if ((i -= n2) < n3)            { s = s3;  d = d3; }
    else if ((i -= n3) < n4)            { s = s4;  d = d4; }
    else return;
    float4 v = *(const float4*)(s + i);
    u16x4 o = { f2bf(v.x), f2bf(v.y), f2bf(v.z), f2bf(v.w) };
    *(u16x4*)(d + i) = o;
}

__global__ __launch_bounds__(256)
void ln_kernel(const u16* __restrict__ in, u16* __restrict__ out,
               const float* __restrict__ g, const float* __restrict__ b)
{
    const int row = blockIdx.x;
    const int t = threadIdx.x;
    const u16* r = in + (long)row * 1024;
    float x[4];
    float s = 0.f, s2 = 0.f;
    #pragma unroll
    for (int j = 0; j < 4; j++) { x[j] = bf2f(r[t + 256 * j]); s += x[j]; s2 += x[j] * x[j]; }
    __shared__ float sm[8];
    const int lane = t & 63, wid = t >> 6;
    #pragma unroll
    for (int o = 32; o > 0; o >>= 1) { s += __shfl_down(s, o, 64); s2 += __shfl_down(s2, o, 64); }
    if (lane == 0) { sm[wid] = s; sm[4 + wid] = s2; }
    __syncthreads();
    s  = sm[0] + sm[1] + sm[2] + sm[3];
    s2 = sm[4] + sm[5] + sm[6] + sm[7];
    const float mean = s * (1.f / 1024.f);
    const float var  = s2 * (1.f / 1024.f) - mean * mean;
    const float rstd = rsqrtf(var + 1e-5f);
    u16* o = out + (long)row * 1024;
    #pragma unroll
    for (int j = 0; j < 4; j++) {
        int c = t + 256 * j;
        o[c] = f2bf((x[j] - mean) * rstd * g[c] + b[c]);
    }
}

__global__ __launch_bounds__(256)
void softmax_kernel(u16* __restrict__ io)
{
    const int row = blockIdx.x;
    const int t = threadIdx.x;
    u16* r = io + (long)row * 1024;
    float x[4];
    float m = -1e30f;
    #pragma unroll
    for (int j = 0; j < 4; j++) { x[j] = bf2f(r[t + 256 * j]); m = fmaxf(m, x[j]); }
    __shared__ float sm[8];
    const int lane = t & 63, wid = t >> 6;
    #pragma unroll
    for (int o = 32; o > 0; o >>= 1) m = fmaxf(m, __shfl_down(m, o, 64));
    if (lane == 0) sm[wid] = m;
    __syncthreads();
    m = fmaxf(fmaxf(sm[0], sm[1]), fmaxf(sm[2], sm[3]));
    float e[4];
    float s = 0.f;
    #pragma unroll
    for (int j = 0; j < 4; j++) { e[j] = __expf(x[j] - m); s += e[j]; }
    #pragma unroll
    for (int o = 32; o > 0; o >>= 1) s += __shfl_down(s, o, 64);
    if (lane == 0) sm[4 + wid] = s;
    __syncthreads();
    s = sm[4] + sm[5] + sm[6] + sm[7];
    const float inv = 1.f / s;
    #pragma unroll
    for (int j = 0; j < 4; j++) r[t + 256 * j] = f2bf(e[j] * inv);
}

// vT[b][c][t] = qkv[b*S + t][2C + c]
__global__ void transpose_v(const u16* __restrict__ qkv, u16* __restrict__ vT)
{
    __shared__ u16 tile[32][33];
    const int b  = blockIdx.z;
    const int t0 = blockIdx.x * 32;   // S index
    const int c0 = blockIdx.y * 32;   // C index
    const int tx = threadIdx.x, ty = threadIdx.y;
    #pragma unroll
    for (int i = ty; i < 32; i += 8)
        tile[i][tx] = qkv[((long)(b * 2048 + t0 + i)) * 3072 + 2048 + c0 + tx];
    __syncthreads();
    #pragma unroll
    for (int i = ty; i < 32; i += 8)
        vT[((long)(b * 1024 + c0 + i)) * 2048 + t0 + tx] = tile[tx][i];
}

__global__ __launch_bounds__(256)
void add_pe(float* __restrict__ out)
{
    long i = (long)blockIdx.x * 256 + threadIdx.x;
    const int f = (int)(i & 1023);
    const int s = (int)((i >> 10) & 2047);
    const float div = __expf(-(float)f * 0.013491709529261986f);
    const float arg = (float)s * div;
    const float pe = (s & 1) ? cosf(arg) : sinf(arg);
    out[i] += pe;
}

extern "C" void kernel_launch(void* const* d_in, const int* in_sizes, int n_in,
                              void* d_out, int out_size, void* d_ws, size_t ws_size,
                              hipStream_t stream)
{
    const float* x        = (const float*)d_in[0];
    const float* fc_in_w  = (const float*)d_in[1];
    const float* fc_in_b  = (const float*)d_in[2];
    const float* ln_g     = (const float*)d_in[3];
    const float* ln_b     = (const float*)d_in[4];
    const float* qkv_w    = (const float*)d_in[5];
    const float* qkv_b    = (const float*)d_in[6];
    const float* proj_w   = (const float*)d_in[7];
    const float* proj_b   = (const float*)d_in[8];
    const float* fc_out_w = (const float*)d_in[9];
    const float* fc_out_b = (const float*)d_in[10];

    char* w = (char*)d_ws;
    size_t off = 0;
    auto carve = [&](size_t bytes) -> void* {
        void* p = w + off;
        off += (bytes + 255) & ~(size_t)255;
        return p;
    };
    u16* xb   = (u16*)carve(16777216);  // x bf16; reused as hY
    u16* hY   = xb;
    u16* wfci = (u16*)carve(2097152);
    u16* wqkv = (u16*)carve(25165824);
    u16* wprj = (u16*)carve(8388608);
    u16* wfco = (u16*)carve(2097152);
    u16* t0   = (u16*)carve(50331648);  // qkv acts (8192x3072); att aliases
    u16* att  = t0;
    u16* hX   = (u16*)carve(16777216);
    u16* pred = (u16*)carve(16777216);
    u16* vT   = (u16*)carve(16777216);  // (B, C, S)
    u16* sc   = (u16*)carve(33554432);  // scores (B, S, S)

    // fp32 -> bf16, one launch
    cvt_all<<<dim3(26624), dim3(256), 0, stream>>>(
        x, xb, 8388608L, fc_in_w, wfci, 1048576L, qkv_w, wqkv, 12582912L,
        proj_w, wprj, 4194304L, fc_out_w, wfco, 1048576L);

    // fc_in: t0 = x @ fc_in_w^T + b   (8192x1024, K=1024)
    gemm_bt<2><<<dim3(8, 64, 1), 256, 0, stream>>>(xb, 1024, 0, wfci, 1024, 0,
                                                   t0, 1024, 0, fc_in_b, nullptr, 1024, 1.0f);
    ln_kernel<<<8192, 256, 0, stream>>>(t0, hX, ln_g, ln_b);

    const u16* hin[4] = { hX, pred, hX, hY };
    u16* hout[4]      = { pred, hX, hY, hX };

    for (int i = 0; i < 4; i++) {
        // qkv = gelu(h @ qkv_w[i]^T + qkv_b[i])  (8192x3072, K=1024)
        gemm_bt<3><<<dim3(24, 64, 1), 256, 0, stream>>>(hin[i], 1024, 0,
            wqkv + (long)i * 3145728, 1024, 0, t0, 3072, 0,
            qkv_b + (long)i * 3072, nullptr, 1024, 1.0f);
        transpose_v<<<dim3(64, 32, 4), dim3(32, 8), 0, stream>>>(t0, vT);
        // scores = q @ k^T * (1/C)   (per batch 2048x2048, K=1024)
        gemm_bt<1><<<dim3(16, 16, 4), 256, 0, stream>>>(t0, 3072, 6291456,
            t0 + 1024, 3072, 6291456, sc, 2048, 4194304,
            nullptr, nullptr, 1024, 1.0f / 1024.0f);
        // att = scores @ v   (per batch 2048x1024, K=2048)
        gemm_bt<0><<<dim3(8, 16, 4), 256, 0, stream>>>(sc, 2048, 4194304,
            vT, 2048, 2097152, att, 1024, 2097152,
            nullptr, nullptr, 2048, 1.0f);
        softmax_kernel<<<8192, 256, 0, stream>>>(att);
        // h = gelu(att @ proj_w[i]^T + proj_b[i]) [+ pred for i>0]
        if (i == 0)
            gemm_bt<3><<<dim3(8, 64, 1), 256, 0, stream>>>(att, 1024, 0,
                wprj, 1024, 0, hout[0], 1024, 0, proj_b, nullptr, 1024, 1.0f);
        else
            gemm_bt<4><<<dim3(8, 64, 1), 256, 0, stream>>>(att, 1024, 0,
                wprj + (long)i * 1048576, 1024, 0, hout[i], 1024, 0,
                proj_b + (long)i * 1024, pred, 1024, 1.0f);
    }

    gemm_bt<5><<<dim3(8, 64, 1), 256, 0, stream>>>(hX, 1024, 0, wfco, 1024, 0,
                                                   d_out, 1024, 0, fc_out_b, nullptr, 1024, 1.0f);
    add_pe<<<32768, 256, 0, stream>>>((float*)d_out);
}

// Round 5
// 1046.667 us; speedup vs baseline: 1.3878x; 1.0219x over previous
//
#include <hip/hip_runtime.h>
#include <math.h>

typedef unsigned short u16;
typedef __bf16 bf16x8 __attribute__((ext_vector_type(8)));
typedef float f32x4  __attribute__((ext_vector_type(4)));
typedef float f32x16 __attribute__((ext_vector_type(16)));
typedef u16   u16x4  __attribute__((ext_vector_type(4)));
typedef u16   u16x8  __attribute__((ext_vector_type(8)));

#define GPTR(p) ((__attribute__((address_space(1))) void*)(p))
#define LPTR(p) ((__attribute__((address_space(3))) void*)(p))

__device__ __forceinline__ float bf2f(u16 h) { return __uint_as_float(((unsigned)h) << 16); }
__device__ __forceinline__ u16 f2bf(float f) {
    unsigned u = __float_as_uint(f);
    return (u16)((u + 0x7fffu + ((u >> 16) & 1u)) >> 16);
}
// tanh-form gelu, ~8 VALU ops
__device__ __forceinline__ float gelu_f(float x) {
    float u = 0.7978845608f * x * (1.0f + 0.044715f * x * x);
    float e = __expf(2.0f * u);
    float t = 1.0f - 2.0f / (e + 1.0f);
    return 0.5f * x * (1.0f + t);
}

// ---------------------------------------------------------------------------
// GEMM: C = epilogue(A(MxK) @ B(NxK)^T), bf16 in, fp32 acc.
// 128x128 block tile, 4 waves of 64x64, BK=64, mfma_f32_32x32x16_bf16.
//
// A path (always LDS): 128 rows x 64 k, slot(row,kc) = row*8 + (kc^(row&7)),
//   staged via global_load_lds width 16 (coalesced 128B/row reads),
//   fragment ds_read_b128 conflict-free (bank-group = kc^(m32&7)).
//
// B path, BG=1 (pre-granuled weights): B is stored in MFMA-fragment order:
//   granule block (nt, kt) of 1KB holds lane l -> B[nt*32+(l&31)][kt*16+(l>>5)*8+j]
//   -> per k-step one coalesced global_load_dwordx4 straight into VGPRs.
//   LDS traffic halves; B loads need no barrier protection.
// B path, BG=0 (activations): LDS-staged like A.
//
// Epilogue: per-wave 4KB LDS slice round-trip, wide stores.
// MODE: 0=none, 1=scale, 2=+bias, 3=+bias,gelu, 4=+bias,gelu,+addend, 5=+bias fp32-out
// ---------------------------------------------------------------------------
template<int MODE, int BG>
__global__ __launch_bounds__(256, 4)
void gemm_bt(const u16* __restrict__ A, int lda, long sA,
             const u16* __restrict__ B, int ldb, long sB,
             void* __restrict__ Cout, int ldc, long sC,
             const float* __restrict__ bias,
             const u16* __restrict__ addend,
             int K, float scale)
{
    __shared__ u16 lds[BG ? 8192 : 16384];
    u16* lA = lds;
    u16* lB = lds + 8192;               // only used when BG==0
    const int t    = threadIdx.x;
    const int lane = t & 63;
    const int wid  = t >> 6;
    const int wm   = (wid & 1) * 64;
    const int wn   = (wid >> 1) * 64;
    const int m32  = lane & 31;
    const int h    = lane >> 5;
    const int bz   = blockIdx.z;

    const long rowA0 = (long)blockIdx.y * 128;
    const long colB0 = (long)blockIdx.x * 128;
    const u16* Ab = A + (long)bz * sA + rowA0 * lda;

    // A staging: inst j, thread t -> row j*32+(t>>3), chunk (t&7)^((t>>3)&7)
    const int rt  = t >> 3;
    const int kcg = ((t & 7) ^ (rt & 7)) * 8;
    const u16* gA[4];
    #pragma unroll
    for (int j = 0; j < 4; j++) gA[j] = Ab + (long)(j * 32 + rt) * lda + kcg;
    u16* dA = lA + t * 8;

    // B setup
    const u16* gB[4]; u16* dB = lB + t * 8;           // BG==0
    const u16* gb0 = nullptr; const u16* gb1 = nullptr; // BG==1
    if constexpr (BG) {
        const int nt0 = (int)((colB0 + wn) >> 5);
        gb0 = B + (long)nt0 * (K >> 4) * 512 + lane * 8;
        gb1 = gb0 + (long)(K >> 4) * 512;
    } else {
        const u16* Bb = B + (long)bz * sB + colB0 * ldb;
        #pragma unroll
        for (int j = 0; j < 4; j++) gB[j] = Bb + (long)(j * 32 + rt) * ldb + kcg;
    }

    f32x16 acc[2][2];
    #pragma unroll
    for (int i = 0; i < 2; i++)
        #pragma unroll
        for (int j = 0; j < 2; j++)
            #pragma unroll
            for (int r = 0; r < 16; r++) acc[i][j][r] = 0.f;

    const int sg = m32 & 7;
    const u16* fA[4]; const u16* fB[4];
    #pragma unroll
    for (int kh = 0; kh < 4; kh++) {
        fA[kh] = lA + (wm + m32) * 64 + 8 * ((kh * 2 + h) ^ sg);
        if constexpr (!BG) fB[kh] = lB + (wn + m32) * 64 + 8 * ((kh * 2 + h) ^ sg);
    }

    for (int k0 = 0; k0 < K; k0 += 64) {
        #pragma unroll
        for (int j = 0; j < 4; j++)
            __builtin_amdgcn_global_load_lds(GPTR(gA[j] + k0), LPTR(dA + j * 2048), 16, 0, 0);
        bf16x8 bg[2][4];
        if constexpr (BG) {
            #pragma unroll
            for (int kh = 0; kh < 4; kh++) {
                bg[0][kh] = *(const bf16x8*)(gb0 + (long)k0 * 32 + kh * 512);
                bg[1][kh] = *(const bf16x8*)(gb1 + (long)k0 * 32 + kh * 512);
            }
        } else {
            #pragma unroll
            for (int j = 0; j < 4; j++)
                __builtin_amdgcn_global_load_lds(GPTR(gB[j] + k0), LPTR(dB + j * 2048), 16, 0, 0);
        }
        __syncthreads();
        #pragma unroll
        for (int kh = 0; kh < 4; kh++) {
            bf16x8 a0 = *(const bf16x8*)(fA[kh]);
            bf16x8 a1 = *(const bf16x8*)(fA[kh] + 2048);
            bf16x8 b0, b1;
            if constexpr (BG) { b0 = bg[0][kh]; b1 = bg[1][kh]; }
            else {
                b0 = *(const bf16x8*)(fB[kh]);
                b1 = *(const bf16x8*)(fB[kh] + 2048);
            }
            acc[0][0] = __builtin_amdgcn_mfma_f32_32x32x16_bf16(a0, b0, acc[0][0], 0, 0, 0);
            acc[0][1] = __builtin_amdgcn_mfma_f32_32x32x16_bf16(a0, b1, acc[0][1], 0, 0, 0);
            acc[1][0] = __builtin_amdgcn_mfma_f32_32x32x16_bf16(a1, b0, acc[1][0], 0, 0, 0);
            acc[1][1] = __builtin_amdgcn_mfma_f32_32x32x16_bf16(a1, b1, acc[1][1], 0, 0, 0);
        }
        __syncthreads();
    }

    float* Cf = (float*)Cout + (long)bz * sC;
    u16*   Cu = (u16*)Cout + (long)bz * sC;
    float* sw_ = (float*)lds + wid * 1024;      // per-wave 4KB slice
    const long rb = rowA0 + wm;
    const long cb = colB0 + wn;
    const int prow = lane >> 3;
    const int c4   = (lane & 7) * 4;
    // C/D layout (m74/m101): col = lane&31, row = (reg&3) + 8*(reg>>2) + 4*(lane>>5)
    #pragma unroll
    for (int mi = 0; mi < 2; mi++) {
        #pragma unroll
        for (int ni = 0; ni < 2; ni++) {
            #pragma unroll
            for (int r = 0; r < 16; r++)
                sw_[((r & 3) + 8 * (r >> 2) + 4 * h) * 32 + m32] = acc[mi][ni][r];
            #pragma unroll
            for (int p = 0; p < 4; p++) {
                const int  row  = p * 8 + prow;
                const long grow = rb + mi * 32 + row;
                const long gcol = cb + ni * 32 + c4;
                f32x4 v = *(const f32x4*)&sw_[row * 32 + c4];
                float4 bvv = {0.f, 0.f, 0.f, 0.f};
                if constexpr (MODE >= 2) bvv = *(const float4*)&bias[gcol];
                if constexpr (MODE == 1) {
                    #pragma unroll
                    for (int e = 0; e < 4; e++) v[e] *= scale;
                }
                v[0] += bvv.x; v[1] += bvv.y; v[2] += bvv.z; v[3] += bvv.w;
                if constexpr (MODE == 3 || MODE == 4) {
                    #pragma unroll
                    for (int e = 0; e < 4; e++) v[e] = gelu_f(v[e]);
                }
                if constexpr (MODE == 4) {
                    u16x4 ad = *(const u16x4*)&addend[grow * (long)ldc + gcol];
                    #pragma unroll
                    for (int e = 0; e < 4; e++) v[e] += bf2f(ad[e]);
                }
                if constexpr (MODE == 5) {
                    *(f32x4*)&Cf[grow * (long)ldc + gcol] = v;
                } else {
                    u16x4 o = { f2bf(v[0]), f2bf(v[1]), f2bf(v[2]), f2bf(v[3]) };
                    *(u16x4*)&Cu[grow * (long)ldc + gcol] = o;
                }
            }
        }
    }
}

// x fp32 -> bf16 plain
__global__ __launch_bounds__(256)
void cvt_x(const float* __restrict__ in, u16* __restrict__ out, long n)
{
    long i = ((long)blockIdx.x * 256 + threadIdx.x) * 4;
    if (i < n) {
        float4 v = *(const float4*)(in + i);
        u16x4 o = { f2bf(v.x), f2bf(v.y), f2bf(v.z), f2bf(v.w) };
        *(u16x4*)(out + i) = o;
    }
}

// All weights fp32 [n][k] (K=1024) -> bf16 granule layout:
//   granule block (nt, kt): 1KB, lane l -> W[nt*32+(l&31)][kt*16+(l>>5)*8 + j]
// Block handles one 32n x 64k slab. nt rows: qkv [0,384), proj [384,512),
// fc_in [512,544), fc_out [544,576).
__global__ __launch_bounds__(256)
void cvt_wg(const float* __restrict__ qkvw, u16* __restrict__ dqkv,
            const float* __restrict__ projw, u16* __restrict__ dproj,
            const float* __restrict__ fciw, u16* __restrict__ dfci,
            const float* __restrict__ fcow, u16* __restrict__ dfco)
{
    __shared__ u16 sl[2048];
    const int nt = blockIdx.y;
    const int ks = blockIdx.x;          // k-slab: k0 = ks*64
    const int t  = threadIdx.x;
    const float* src; u16* dst; int nl;
    if      (nt < 384) { src = qkvw;  dst = dqkv;  nl = nt; }
    else if (nt < 512) { src = projw; dst = dproj; nl = nt - 384; }
    else if (nt < 544) { src = fciw;  dst = dfci;  nl = nt - 512; }
    else               { src = fcow;  dst = dfco;  nl = nt - 544; }
    const int n32 = t >> 3;
    const int kq  = t & 7;
    const float* s = src + ((long)nl * 32 + n32) * 1024 + ks * 64 + kq * 8;
    float4 v0 = *(const float4*)s;
    float4 v1 = *(const float4*)(s + 4);
    u16x8 o = { f2bf(v0.x), f2bf(v0.y), f2bf(v0.z), f2bf(v0.w),
                f2bf(v1.x), f2bf(v1.y), f2bf(v1.z), f2bf(v1.w) };
    const int slot = (kq >> 1) * 64 + (kq & 1) * 32 + n32;
    *(u16x8*)&sl[slot * 8] = o;
    __syncthreads();
    u16* d = dst + (long)nl * 32768 + ks * 2048 + t * 8;
    *(u16x8*)d = *(const u16x8*)&sl[t * 8];
}

__global__ __launch_bounds__(256)
void ln_kernel(const u16* __restrict__ in, u16* __restrict__ out,
               const float* __restrict__ g, const float* __restrict__ b)
{
    const int row = blockIdx.x;
    const int t = threadIdx.x;
    const u16* r = in + (long)row * 1024;
    float x[4];
    float s = 0.f, s2 = 0.f;
    #pragma unroll
    for (int j = 0; j < 4; j++) { x[j] = bf2f(r[t + 256 * j]); s += x[j]; s2 += x[j] * x[j]; }
    __shared__ float sm[8];
    const int lane = t & 63, wid = t >> 6;
    #pragma unroll
    for (int o = 32; o > 0; o >>= 1) { s += __shfl_down(s, o, 64); s2 += __shfl_down(s2, o, 64); }
    if (lane == 0) { sm[wid] = s; sm[4 + wid] = s2; }
    __syncthreads();
    s  = sm[0] + sm[1] + sm[2] + sm[3];
    s2 = sm[4] + sm[5] + sm[6] + sm[7];
    const float mean = s * (1.f / 1024.f);
    const float var  = s2 * (1.f / 1024.f) - mean * mean;
    const float rstd = rsqrtf(var + 1e-5f);
    u16* o = out + (long)row * 1024;
    #pragma unroll
    for (int j = 0; j < 4; j++) {
        int c = t + 256 * j;
        o[c] = f2bf((x[j] - mean) * rstd * g[c] + b[c]);
    }
}

__global__ __launch_bounds__(256)
void softmax_kernel(u16* __restrict__ io)
{
    const int row = blockIdx.x;
    const int t = threadIdx.x;
    u16* r = io + (long)row * 1024;
    float x[4];
    float m = -1e30f;
    #pragma unroll
    for (int j = 0; j < 4; j++) { x[j] = bf2f(r[t + 256 * j]); m = fmaxf(m, x[j]); }
    __shared__ float sm[8];
    const int lane = t & 63, wid = t >> 6;
    #pragma unroll
    for (int o = 32; o > 0; o >>= 1) m = fmaxf(m, __shfl_down(m, o, 64));
    if (lane == 0) sm[wid] = m;
    __syncthreads();
    m = fmaxf(fmaxf(sm[0], sm[1]), fmaxf(sm[2], sm[3]));
    float e[4];
    float s = 0.f;
    #pragma unroll
    for (int j = 0; j < 4; j++) { e[j] = __expf(x[j] - m); s += e[j]; }
    #pragma unroll
    for (int o = 32; o > 0; o >>= 1) s += __shfl_down(s, o, 64);
    if (lane == 0) sm[4 + wid] = s;
    __syncthreads();
    s = sm[4] + sm[5] + sm[6] + sm[7];
    const float inv = 1.f / s;
    #pragma unroll
    for (int j = 0; j < 4; j++) r[t + 256 * j] = f2bf(e[j] * inv);
}

// vT[b][c][t] = qkv[b*S + t][2C + c]
__global__ void transpose_v(const u16* __restrict__ qkv, u16* __restrict__ vT)
{
    __shared__ u16 tile[32][33];
    const int b  = blockIdx.z;
    const int t0 = blockIdx.x * 32;
    const int c0 = blockIdx.y * 32;
    const int tx = threadIdx.x, ty = threadIdx.y;
    #pragma unroll
    for (int i = ty; i < 32; i += 8)
        tile[i][tx] = qkv[((long)(b * 2048 + t0 + i)) * 3072 + 2048 + c0 + tx];
    __syncthreads();
    #pragma unroll
    for (int i = ty; i < 32; i += 8)
        vT[((long)(b * 1024 + c0 + i)) * 2048 + t0 + tx] = tile[tx][i];
}

__global__ __launch_bounds__(256)
void add_pe(float* __restrict__ out)
{
    long i = (long)blockIdx.x * 256 + threadIdx.x;
    const int f = (int)(i & 1023);
    const int s = (int)((i >> 10) & 2047);
    const float div = __expf(-(float)f * 0.013491709529261986f);
    const float arg = (float)s * div;
    const float pe = (s & 1) ? cosf(arg) : sinf(arg);
    out[i] += pe;
}

extern "C" void kernel_launch(void* const* d_in, const int* in_sizes, int n_in,
                              void* d_out, int out_size, void* d_ws, size_t ws_size,
                              hipStream_t stream)
{
    const float* x        = (const float*)d_in[0];
    const float* fc_in_w  = (const float*)d_in[1];
    const float* fc_in_b  = (const float*)d_in[2];
    const float* ln_g     = (const float*)d_in[3];
    const float* ln_b     = (const float*)d_in[4];
    const float* qkv_w    = (const float*)d_in[5];
    const float* qkv_b    = (const float*)d_in[6];
    const float* proj_w   = (const float*)d_in[7];
    const float* proj_b   = (const float*)d_in[8];
    const float* fc_out_w = (const float*)d_in[9];
    const float* fc_out_b = (const float*)d_in[10];

    char* w = (char*)d_ws;
    size_t off = 0;
    auto carve = [&](size_t bytes) -> void* {
        void* p = w + off;
        off += (bytes + 255) & ~(size_t)255;
        return p;
    };
    u16* xb   = (u16*)carve(16777216);  // x bf16; reused as hY
    u16* hY   = xb;
    u16* wfci = (u16*)carve(2097152);   // granule layout
    u16* wqkv = (u16*)carve(25165824);  // granule layout
    u16* wprj = (u16*)carve(8388608);   // granule layout
    u16* wfco = (u16*)carve(2097152);   // granule layout
    u16* t0   = (u16*)carve(50331648);  // qkv acts (8192x3072); att aliases
    u16* att  = t0;
    u16* hX   = (u16*)carve(16777216);
    u16* pred = (u16*)carve(16777216);
    u16* vT   = (u16*)carve(16777216);  // (B, C, S)
    u16* sc   = (u16*)carve(33554432);  // scores (B, S, S)

    cvt_x<<<dim3(8192), dim3(256), 0, stream>>>(x, xb, 8388608L);
    cvt_wg<<<dim3(16, 576), dim3(256), 0, stream>>>(qkv_w, wqkv, proj_w, wprj,
                                                    fc_in_w, wfci, fc_out_w, wfco);

    // fc_in: t0 = x @ fc_in_w^T + b   (8192x1024, K=1024)
    gemm_bt<2,1><<<dim3(8, 64, 1), 256, 0, stream>>>(xb, 1024, 0, wfci, 0, 0,
                                                     t0, 1024, 0, fc_in_b, nullptr, 1024, 1.0f);
    ln_kernel<<<8192, 256, 0, stream>>>(t0, hX, ln_g, ln_b);

    const u16* hin[4] = { hX, pred, hX, hY };
    u16* hout[4]      = { pred, hX, hY, hX };

    for (int i = 0; i < 4; i++) {
        // qkv = gelu(h @ qkv_w[i]^T + qkv_b[i])  (8192x3072, K=1024)
        gemm_bt<3,1><<<dim3(24, 64, 1), 256, 0, stream>>>(hin[i], 1024, 0,
            wqkv + (long)i * 3145728, 0, 0, t0, 3072, 0,
            qkv_b + (long)i * 3072, nullptr, 1024, 1.0f);
        transpose_v<<<dim3(64, 32, 4), dim3(32, 8), 0, stream>>>(t0, vT);
        // scores = q @ k^T * (1/C)   (per batch 2048x2048, K=1024)
        gemm_bt<1,0><<<dim3(16, 16, 4), 256, 0, stream>>>(t0, 3072, 6291456,
            t0 + 1024, 3072, 6291456, sc, 2048, 4194304,
            nullptr, nullptr, 1024, 1.0f / 1024.0f);
        // att = scores @ v   (per batch 2048x1024, K=2048)
        gemm_bt<0,0><<<dim3(8, 16, 4), 256, 0, stream>>>(sc, 2048, 4194304,
            vT, 2048, 2097152, att, 1024, 2097152,
            nullptr, nullptr, 2048, 1.0f);
        softmax_kernel<<<8192, 256, 0, stream>>>(att);
        // h = gelu(att @ proj_w[i]^T + proj_b[i]) [+ pred for i>0]
        if (i == 0)
            gemm_bt<3,1><<<dim3(8, 64, 1), 256, 0, stream>>>(att, 1024, 0,
                wprj, 0, 0, hout[0], 1024, 0, proj_b, nullptr, 1024, 1.0f);
        else
            gemm_bt<4,1><<<dim3(8, 64, 1), 256, 0, stream>>>(att, 1024, 0,
                wprj + (long)i * 1048576, 0, 0, hout[i], 1024, 0,
                proj_b + (long)i * 1024, pred, 1024, 1.0f);
    }

    gemm_bt<5,1><<<dim3(8, 64, 1), 256, 0, stream>>>(hX, 1024, 0, wfco, 0, 0,
                                                     d_out, 1024, 0, fc_out_b, nullptr, 1024, 1.0f);
    add_pe<<<32768, 256, 0, stream>>>((float*)d_out);
}

// Round 6
// 1045.449 us; speedup vs baseline: 1.3895x; 1.0012x over previous
//
#include <hip/hip_runtime.h>
#include <math.h>

typedef unsigned short u16;
typedef __bf16 bf16x8 __attribute__((ext_vector_type(8)));
typedef float f32x4  __attribute__((ext_vector_type(4)));
typedef float f32x16 __attribute__((ext_vector_type(16)));
typedef u16   u16x4  __attribute__((ext_vector_type(4)));
typedef u16   u16x8  __attribute__((ext_vector_type(8)));

#define GPTR(p) ((__attribute__((address_space(1))) void*)(p))
#define LPTR(p) ((__attribute__((address_space(3))) void*)(p))

__device__ __forceinline__ float bf2f(u16 h) { return __uint_as_float(((unsigned)h) << 16); }
__device__ __forceinline__ u16 f2bf(float f) {
    unsigned u = __float_as_uint(f);
    return (u16)((u + 0x7fffu + ((u >> 16) & 1u)) >> 16);
}
// tanh-form gelu, ~8 VALU ops
__device__ __forceinline__ float gelu_f(float x) {
    float u = 0.7978845608f * x * (1.0f + 0.044715f * x * x);
    float e = __expf(2.0f * u);
    float t = 1.0f - 2.0f / (e + 1.0f);
    return 0.5f * x * (1.0f + t);
}

// ---------------------------------------------------------------------------
// Pipelined GEMM: C = epi(A(MxK) @ B(NxK)^T), bf16 in, fp32 acc.
// 128x128 tile, 4 waves of 64x64, BK=64, mfma_f32_32x32x16_bf16.
// A: LDS double-buffered (2x16KB), staged via global_load_lds w16,
//    slot(row,kc)=row*8+(kc^(row&7)) -> coalesced stage + conflict-free reads.
// B: pre-granuled in memory (granule block (nt,kt): 1KB, lane l ->
//    B[nt*32+(l&31)][kt*16+(l>>5)*8+j]) -> coalesced dwordx4 into VGPRs.
// K-loop: ONE barrier/iter; A(it+1)/B(it+1) prefetch issued right after the
// barrier so the next barrier's vmcnt(0) drain is residual, not full-latency.
// Epilogue: per-wave 4KB LDS slice (col-swizzled), wide stores.
// MODE: 0 none | 1 scale | 2 +bias | 3 +bias,gelu | 4 +bias,gelu,+addend
//       5 +bias fp32-out | 6 qkv: +bias,gelu, q normal / k,v granule
// ---------------------------------------------------------------------------
template<int MODE>
__global__ __launch_bounds__(256, 3)
void gemm_g(const u16* __restrict__ A, int lda, long sA,
            const u16* __restrict__ B, long sB,
            void* __restrict__ Cout, int ldc, long sC,
            const float* __restrict__ bias,
            const u16* __restrict__ addend,
            u16* __restrict__ kgr, u16* __restrict__ vgr,
            int K, float scale)
{
    __shared__ u16 lds[16384];          // 32 KB = 2 x 16KB A buffers
    u16* lA = lds;
    const int t    = threadIdx.x;
    const int lane = t & 63;
    const int wid  = t >> 6;
    const int wm   = (wid & 1) * 64;
    const int wn   = (wid >> 1) * 64;
    const int m32  = lane & 31;
    const int h    = lane >> 5;
    const int bz   = blockIdx.z;

    const long rowA0 = (long)blockIdx.y * 128;
    const long colB0 = (long)blockIdx.x * 128;
    const u16* Ab = A + (long)bz * sA + rowA0 * lda;

    // A staging: inst j, thread t -> row j*32+(t>>3), chunk (t&7)^((t>>3)&7)
    const int rt  = t >> 3;
    const int kcg = ((t & 7) ^ (rt & 7)) * 8;
    const u16* gA[4];
    #pragma unroll
    for (int j = 0; j < 4; j++) gA[j] = Ab + (long)(j * 32 + rt) * lda + kcg;
    u16* dA = lA + t * 8;

    // B granule pointers (two 32-row n-blocks per wave)
    const int nt0 = (int)((colB0 + wn) >> 5);
    const long ktn = (long)(K >> 4) * 512;      // u16 per nt row
    const u16* gb0 = B + (long)bz * sB + (long)nt0 * ktn + lane * 8;
    const u16* gb1 = gb0 + ktn;

    f32x16 acc[2][2];
    #pragma unroll
    for (int i = 0; i < 2; i++)
        #pragma unroll
        for (int j = 0; j < 2; j++)
            #pragma unroll
            for (int r = 0; r < 16; r++) acc[i][j][r] = 0.f;

    const int sg = m32 & 7;
    const u16* fA[4];
    #pragma unroll
    for (int kh = 0; kh < 4; kh++)
        fA[kh] = lA + (wm + m32) * 64 + 8 * ((kh * 2 + h) ^ sg);

    // prologue: A -> buf0, B slab 0 -> regs
    #pragma unroll
    for (int j = 0; j < 4; j++)
        __builtin_amdgcn_global_load_lds(GPTR(gA[j]), LPTR(dA + j * 2048), 16, 0, 0);
    bf16x8 bc[2][4], bn[2][4];
    #pragma unroll
    for (int kh = 0; kh < 4; kh++) {
        bc[0][kh] = *(const bf16x8*)(gb0 + kh * 512);
        bc[1][kh] = *(const bf16x8*)(gb1 + kh * 512);
    }

    const int niter = K >> 6;
    for (int it = 0; it < niter; ++it) {
        __syncthreads();                         // buf[it&1] ready (loads had ~1 iter)
        const int kn = (it + 1) << 6;
        if (kn < K) {                            // prefetch next slab
            const int nb = (it + 1) & 1;
            #pragma unroll
            for (int j = 0; j < 4; j++)
                __builtin_amdgcn_global_load_lds(GPTR(gA[j] + kn),
                                                 LPTR(dA + nb * 8192 + j * 2048), 16, 0, 0);
            #pragma unroll
            for (int kh = 0; kh < 4; kh++) {
                bn[0][kh] = *(const bf16x8*)(gb0 + (long)kn * 32 + kh * 512);
                bn[1][kh] = *(const bf16x8*)(gb1 + (long)kn * 32 + kh * 512);
            }
        }
        const int cbo = (it & 1) * 8192;
        #pragma unroll
        for (int kh = 0; kh < 4; kh++) {
            bf16x8 a0 = *(const bf16x8*)(fA[kh] + cbo);
            bf16x8 a1 = *(const bf16x8*)(fA[kh] + cbo + 2048);
            acc[0][0] = __builtin_amdgcn_mfma_f32_32x32x16_bf16(a0, bc[0][kh], acc[0][0], 0, 0, 0);
            acc[0][1] = __builtin_amdgcn_mfma_f32_32x32x16_bf16(a0, bc[1][kh], acc[0][1], 0, 0, 0);
            acc[1][0] = __builtin_amdgcn_mfma_f32_32x32x16_bf16(a1, bc[0][kh], acc[1][0], 0, 0, 0);
            acc[1][1] = __builtin_amdgcn_mfma_f32_32x32x16_bf16(a1, bc[1][kh], acc[1][1], 0, 0, 0);
        }
        #pragma unroll
        for (int kh = 0; kh < 4; kh++) { bc[0][kh] = bn[0][kh]; bc[1][kh] = bn[1][kh]; }
    }
    // niter is even (K=1024/2048): last consumed buffer = buf1, sw_ lives in buf0.

    float* Cf = (float*)Cout + (long)bz * sC;
    u16*   Cu = (u16*)Cout + (long)bz * sC;
    float* sw_ = (float*)lds + wid * 1024;      // per-wave 4KB slice (buf0)
    const long rb = rowA0 + wm;
    const long cb = colB0 + wn;
    const int prow = lane >> 3;
    const int c4   = (lane & 7) * 4;
    // C/D layout: col = lane&31, row = (r&3) + 8*(r>>2) + 4*(lane>>5)
    // slice stored col-swizzled: col' = col ^ ((row&3)*8)
    #pragma unroll
    for (int mi = 0; mi < 2; mi++) {
        #pragma unroll
        for (int ni = 0; ni < 2; ni++) {
            const int colg = (int)(cb + ni * 32 + m32);
            float bv = 0.0f;
            if constexpr (MODE >= 2) bv = bias[colg];
            #pragma unroll
            for (int r = 0; r < 16; r++) {
                float v = acc[mi][ni][r];
                if constexpr (MODE == 1) v *= scale;
                v += bv;
                if constexpr (MODE == 3 || MODE == 4 || MODE == 6) v = gelu_f(v);
                const int rowfn = (r & 3) + 8 * (r >> 2) + 4 * h;
                sw_[rowfn * 32 + (m32 ^ ((rowfn & 3) * 8))] = v;
            }
            const int seg = (MODE == 6) ? (int)(colB0 >> 10) : 0;
            if (MODE != 6 || seg == 0) {
                // normal path: wide stores
                #pragma unroll
                for (int p = 0; p < 4; p++) {
                    const int  row  = p * 8 + prow;
                    const long grow = rb + mi * 32 + row;
                    const long gcol = cb + ni * 32 + c4;
                    const int  key  = (row & 3) * 8;
                    f32x4 v = *(const f32x4*)&sw_[row * 32 + (c4 ^ key)];
                    if constexpr (MODE == 4) {
                        u16x4 ad = *(const u16x4*)&addend[grow * (long)ldc + gcol];
                        #pragma unroll
                        for (int e = 0; e < 4; e++) v[e] += bf2f(ad[e]);
                    }
                    if constexpr (MODE == 5) {
                        *(f32x4*)&Cf[grow * (long)ldc + gcol] = v;
                    } else {
                        u16x4 o = { f2bf(v[0]), f2bf(v[1]), f2bf(v[2]), f2bf(v[3]) };
                        *(u16x4*)&Cu[grow * (long)ldc + gcol] = o;
                    }
                }
            } else if (seg == 1) {
                // k -> granule layout: B[n=t][k=c]
                const int b   = (int)(rb >> 11);
                const int nt  = ((int)(rb & 2047) + mi * 32) >> 5;
                const int kt0 = ((int)cb + ni * 32 - 1024) >> 4;
                u16* base = kgr + (long)b * 2097152 + ((long)(nt * 64 + kt0) * 64 + lane) * 8;
                #pragma unroll
                for (int q2 = 0; q2 < 2; q2++) {
                    const int g0  = q2 * 16 + h * 8;
                    const int key = (m32 & 3) * 8;
                    f32x4 u0 = *(const f32x4*)&sw_[m32 * 32 + (g0 ^ key)];
                    f32x4 u1 = *(const f32x4*)&sw_[m32 * 32 + (g0 ^ key) + 4];
                    u16x8 o = { f2bf(u0[0]), f2bf(u0[1]), f2bf(u0[2]), f2bf(u0[3]),
                                f2bf(u1[0]), f2bf(u1[1]), f2bf(u1[2]), f2bf(u1[3]) };
                    *(u16x8*)(base + q2 * 512) = o;
                }
            } else {
                // v -> transposed granule: B[n=c][k=t]
                const int b   = (int)(rb >> 11);
                const int kt0 = ((int)(rb & 2047) + mi * 32) >> 4;
                const int nt  = ((int)cb + ni * 32 - 2048) >> 5;
                u16* base = vgr + (long)b * 2097152 + ((long)(nt * 128 + kt0) * 64 + lane) * 8;
                #pragma unroll
                for (int q2 = 0; q2 < 2; q2++) {
                    float vv[8];
                    #pragma unroll
                    for (int j = 0; j < 8; j++) {
                        const int r = q2 * 16 + h * 8 + j;
                        vv[j] = sw_[r * 32 + (m32 ^ ((r & 3) * 8))];
                    }
                    u16x8 o = { f2bf(vv[0]), f2bf(vv[1]), f2bf(vv[2]), f2bf(vv[3]),
                                f2bf(vv[4]), f2bf(vv[5]), f2bf(vv[6]), f2bf(vv[7]) };
                    *(u16x8*)(base + q2 * 512) = o;
                }
            }
        }
    }
}

// x fp32 -> bf16 plain
__global__ __launch_bounds__(256)
void cvt_x(const float* __restrict__ in, u16* __restrict__ out, long n)
{
    long i = ((long)blockIdx.x * 256 + threadIdx.x) * 4;
    if (i < n) {
        float4 v = *(const float4*)(in + i);
        u16x4 o = { f2bf(v.x), f2bf(v.y), f2bf(v.z), f2bf(v.w) };
        *(u16x4*)(out + i) = o;
    }
}

// All weights fp32 [n][k] (K=1024) -> bf16 granule layout.
__global__ __launch_bounds__(256)
void cvt_wg(const float* __restrict__ qkvw, u16* __restrict__ dqkv,
            const float* __restrict__ projw, u16* __restrict__ dproj,
            const float* __restrict__ fciw, u16* __restrict__ dfci,
            const float* __restrict__ fcow, u16* __restrict__ dfco)
{
    __shared__ u16 sl[2048];
    const int nt = blockIdx.y;
    const int ks = blockIdx.x;
    const int t  = threadIdx.x;
    const float* src; u16* dst; int nl;
    if      (nt < 384) { src = qkvw;  dst = dqkv;  nl = nt; }
    else if (nt < 512) { src = projw; dst = dproj; nl = nt - 384; }
    else if (nt < 544) { src = fciw;  dst = dfci;  nl = nt - 512; }
    else               { src = fcow;  dst = dfco;  nl = nt - 544; }
    const int n32 = t >> 3;
    const int kq  = t & 7;
    const float* s = src + ((long)nl * 32 + n32) * 1024 + ks * 64 + kq * 8;
    float4 v0 = *(const float4*)s;
    float4 v1 = *(const float4*)(s + 4);
    u16x8 o = { f2bf(v0.x), f2bf(v0.y), f2bf(v0.z), f2bf(v0.w),
                f2bf(v1.x), f2bf(v1.y), f2bf(v1.z), f2bf(v1.w) };
    const int slot = (kq >> 1) * 64 + (kq & 1) * 32 + n32;
    *(u16x8*)&sl[slot * 8] = o;
    __syncthreads();
    u16* d = dst + (long)nl * 32768 + ks * 2048 + t * 8;
    *(u16x8*)d = *(const u16x8*)&sl[t * 8];
}

__global__ __launch_bounds__(256)
void ln_kernel(const u16* __restrict__ in, u16* __restrict__ out,
               const float* __restrict__ g, const float* __restrict__ b)
{
    const int row = blockIdx.x;
    const int t = threadIdx.x;
    const u16* r = in + (long)row * 1024;
    float x[4];
    float s = 0.f, s2 = 0.f;
    #pragma unroll
    for (int j = 0; j < 4; j++) { x[j] = bf2f(r[t + 256 * j]); s += x[j]; s2 += x[j] * x[j]; }
    __shared__ float sm[8];
    const int lane = t & 63, wid = t >> 6;
    #pragma unroll
    for (int o = 32; o > 0; o >>= 1) { s += __shfl_down(s, o, 64); s2 += __shfl_down(s2, o, 64); }
    if (lane == 0) { sm[wid] = s; sm[4 + wid] = s2; }
    __syncthreads();
    s  = sm[0] + sm[1] + sm[2] + sm[3];
    s2 = sm[4] + sm[5] + sm[6] + sm[7];
    const float mean = s * (1.f / 1024.f);
    const float var  = s2 * (1.f / 1024.f) - mean * mean;
    const float rstd = rsqrtf(var + 1e-5f);
    u16* o = out + (long)row * 1024;
    #pragma unroll
    for (int j = 0; j < 4; j++) {
        int c = t + 256 * j;
        o[c] = f2bf((x[j] - mean) * rstd * g[c] + b[c]);
    }
}

__global__ __launch_bounds__(256)
void softmax_kernel(u16* __restrict__ io)
{
    const int row = blockIdx.x;
    const int t = threadIdx.x;
    u16* r = io + (long)row * 1024;
    float x[4];
    float m = -1e30f;
    #pragma unroll
    for (int j = 0; j < 4; j++) { x[j] = bf2f(r[t + 256 * j]); m = fmaxf(m, x[j]); }
    __shared__ float sm[8];
    const int lane = t & 63, wid = t >> 6;
    #pragma unroll
    for (int o = 32; o > 0; o >>= 1) m = fmaxf(m, __shfl_down(m, o, 64));
    if (lane == 0) sm[wid] = m;
    __syncthreads();
    m = fmaxf(fmaxf(sm[0], sm[1]), fmaxf(sm[2], sm[3]));
    float e[4];
    float s = 0.f;
    #pragma unroll
    for (int j = 0; j < 4; j++) { e[j] = __expf(x[j] - m); s += e[j]; }
    #pragma unroll
    for (int o = 32; o > 0; o >>= 1) s += __shfl_down(s, o, 64);
    if (lane == 0) sm[4 + wid] = s;
    __syncthreads();
    s = sm[4] + sm[5] + sm[6] + sm[7];
    const float inv = 1.f / s;
    #pragma unroll
    for (int j = 0; j < 4; j++) r[t + 256 * j] = f2bf(e[j] * inv);
}

__global__ __launch_bounds__(256)
void add_pe(float* __restrict__ out)
{
    long i = (long)blockIdx.x * 256 + threadIdx.x;
    const int f = (int)(i & 1023);
    const int s = (int)((i >> 10) & 2047);
    const float div = __expf(-(float)f * 0.013491709529261986f);
    const float arg = (float)s * div;
    const float pe = (s & 1) ? cosf(arg) : sinf(arg);
    out[i] += pe;
}

extern "C" void kernel_launch(void* const* d_in, const int* in_sizes, int n_in,
                              void* d_out, int out_size, void* d_ws, size_t ws_size,
                              hipStream_t stream)
{
    const float* x        = (const float*)d_in[0];
    const float* fc_in_w  = (const float*)d_in[1];
    const float* fc_in_b  = (const float*)d_in[2];
    const float* ln_g     = (const float*)d_in[3];
    const float* ln_b     = (const float*)d_in[4];
    const float* qkv_w    = (const float*)d_in[5];
    const float* qkv_b    = (const float*)d_in[6];
    const float* proj_w   = (const float*)d_in[7];
    const float* proj_b   = (const float*)d_in[8];
    const float* fc_out_w = (const float*)d_in[9];
    const float* fc_out_b = (const float*)d_in[10];

    char* w = (char*)d_ws;
    size_t off = 0;
    auto carve = [&](size_t bytes) -> void* {
        void* p = w + off;
        off += (bytes + 255) & ~(size_t)255;
        return p;
    };
    u16* xb   = (u16*)carve(16777216);  // x bf16; reused as hY
    u16* hY   = xb;
    u16* wfci = (u16*)carve(2097152);   // granule
    u16* wqkv = (u16*)carve(25165824);  // granule
    u16* wprj = (u16*)carve(8388608);   // granule
    u16* wfco = (u16*)carve(2097152);   // granule
    u16* qb   = (u16*)carve(16777216);  // q (also fc_in temp)
    u16* kgr  = (u16*)carve(16777216);  // k granule (B,2048,1024)
    u16* vgr  = (u16*)carve(16777216);  // v^T granule (B,1024,2048)
    u16* att  = (u16*)carve(16777216);
    u16* hX   = (u16*)carve(16777216);
    u16* pred = (u16*)carve(16777216);
    u16* sc   = (u16*)carve(33554432);  // scores bf16 (B,S,S)

    cvt_x<<<dim3(8192), dim3(256), 0, stream>>>(x, xb, 8388608L);
    cvt_wg<<<dim3(16, 576), dim3(256), 0, stream>>>(qkv_w, wqkv, proj_w, wprj,
                                                    fc_in_w, wfci, fc_out_w, wfco);

    // fc_in: qb = x @ fc_in_w^T + b (temp), then LN -> hX
    gemm_g<2><<<dim3(8, 64, 1), 256, 0, stream>>>(xb, 1024, 0, wfci, 0,
        qb, 1024, 0, fc_in_b, nullptr, nullptr, nullptr, 1024, 1.0f);
    ln_kernel<<<8192, 256, 0, stream>>>(qb, hX, ln_g, ln_b);

    const u16* hin[4] = { hX, pred, hX, hY };
    u16* hout[4]      = { pred, hX, hY, hX };

    for (int i = 0; i < 4; i++) {
        // qkv = gelu(h @ qkv_w[i]^T + b): q -> qb, k -> kgr, v -> vgr (granule)
        gemm_g<6><<<dim3(24, 64, 1), 256, 0, stream>>>(hin[i], 1024, 0,
            wqkv + (long)i * 3145728, 0, qb, 1024, 0,
            qkv_b + (long)i * 3072, nullptr, kgr, vgr, 1024, 1.0f);
        // scores = q @ k^T * (1/C)  (per batch 2048x2048, K=1024)
        gemm_g<1><<<dim3(16, 16, 4), 256, 0, stream>>>(qb, 1024, 2097152,
            kgr, 2097152, sc, 2048, 4194304,
            nullptr, nullptr, nullptr, nullptr, 1024, 1.0f / 1024.0f);
        // att = scores @ v  (per batch 2048x1024, K=2048)
        gemm_g<0><<<dim3(8, 16, 4), 256, 0, stream>>>(sc, 2048, 4194304,
            vgr, 2097152, att, 1024, 2097152,
            nullptr, nullptr, nullptr, nullptr, 2048, 1.0f);
        softmax_kernel<<<8192, 256, 0, stream>>>(att);
        // h = gelu(att @ proj_w[i]^T + b) [+ pred for i>0]
        if (i == 0)
            gemm_g<3><<<dim3(8, 64, 1), 256, 0, stream>>>(att, 1024, 0,
                wprj, 0, hout[0], 1024, 0, proj_b, nullptr, nullptr, nullptr, 1024, 1.0f);
        else
            gemm_g<4><<<dim3(8, 64, 1), 256, 0, stream>>>(att, 1024, 0,
                wprj + (long)i * 1048576, 0, hout[i], 1024, 0,
                proj_b + (long)i * 1024, pred, nullptr, nullptr, 1024, 1.0f);
    }

    gemm_g<5><<<dim3(8, 64, 1), 256, 0, stream>>>(hX, 1024, 0, wfco, 0,
        d_out, 1024, 0, fc_out_b, nullptr, nullptr, nullptr, 1024, 1.0f);
    add_pe<<<32768, 256, 0, stream>>>((float*)d_out);
}